// Round 1
// baseline (4496.662 us; speedup 1.0000x reference)
//
#include <hip/hip_runtime.h>
#include <math.h>

#define DM 768
#define DI 1536
#define DS 16
#define DTR 48
#define NLAYER 4
#define LSEQ 1024
#define BATCH 2
#define MTOK (BATCH*LSEQ)

__device__ __forceinline__ float sigmoidf_(float x){ return 1.0f/(1.0f+__expf(-x)); }
__device__ __forceinline__ float siluf_(float x){ return x*sigmoidf_(x); }
__device__ __forceinline__ float softplusf_(float x){
    return fmaxf(x,0.0f) + log1pf(__expf(-fabsf(x)));
}

// ---- fused residual-add + LayerNorm (one block per token, 768 = 256*3) ----
template<int FIRST>
__global__ __launch_bounds__(256) void add_ln_kernel(
        const float* __restrict__ hidden,
        float* __restrict__ residual,
        float* __restrict__ out,
        const float* __restrict__ w,
        const float* __restrict__ b){
    int tok = blockIdx.x;
    int tid = threadIdx.x;
    const float* hrow = hidden + (size_t)tok*DM;
    float* rrow = residual + (size_t)tok*DM;
    float v[3];
    float s = 0.f, ss = 0.f;
    #pragma unroll
    for(int j=0;j<3;j++){
        int idx = tid + j*256;
        float r = FIRST ? 0.f : rrow[idx];
        float x = hrow[idx] + r;
        rrow[idx] = x;
        v[j] = x;
        s += x; ss += x*x;
    }
    __shared__ float red[2][4];
    #pragma unroll
    for(int off=32; off; off>>=1){ s += __shfl_down(s, off); ss += __shfl_down(ss, off); }
    int wave = tid>>6, lane = tid&63;
    if(lane==0){ red[0][wave]=s; red[1][wave]=ss; }
    __syncthreads();
    if(tid==0){
        float ts=0.f, tss=0.f;
        #pragma unroll
        for(int i=0;i<4;i++){ ts+=red[0][i]; tss+=red[1][i]; }
        red[0][0]=ts; red[1][0]=tss;
    }
    __syncthreads();
    float mean = red[0][0]*(1.0f/DM);
    float var  = red[1][0]*(1.0f/DM) - mean*mean;
    float rstd = rsqrtf(var + 1e-5f);
    #pragma unroll
    for(int j=0;j<3;j++){
        int idx = tid + j*256;
        out[(size_t)tok*DM + idx] = (v[j]-mean)*rstd*w[idx] + b[idx];
    }
}

// ---- generic fp32 GEMM: C[m][n] = act(sum_k A[m][k]*W[n][k] (+bias[n])) ----
// A: M x K (row stride lda), W: N x K (row stride K), C: M x N (row stride ldc)
// M multiple of 64; K multiple of 16; N guarded.
template<int ACT>
__global__ __launch_bounds__(256) void gemm_tn(
        const float* __restrict__ A, int lda,
        const float* __restrict__ W,
        const float* __restrict__ bias,
        float* __restrict__ C, int ldc,
        int M, int N, int K){
    alignas(16) __shared__ float As[16][68];
    alignas(16) __shared__ float Ws[16][68];
    int tid = threadIdx.x;
    int m0 = blockIdx.y*64;
    int n0 = blockIdx.x*64;
    int tr = tid>>2;        // 0..63
    int tk = (tid&3)*4;     // 0,4,8,12
    int tx = tid&15, ty = tid>>4;
    float acc[4][4] = {};
    for(int k0=0;k0<K;k0+=16){
        float4 av = *(const float4*)(A + (size_t)(m0+tr)*lda + k0 + tk);
        float4 wv = make_float4(0.f,0.f,0.f,0.f);
        if(n0+tr < N) wv = *(const float4*)(W + (size_t)(n0+tr)*K + k0 + tk);
        __syncthreads();
        As[tk+0][tr]=av.x; As[tk+1][tr]=av.y; As[tk+2][tr]=av.z; As[tk+3][tr]=av.w;
        Ws[tk+0][tr]=wv.x; Ws[tk+1][tr]=wv.y; Ws[tk+2][tr]=wv.z; Ws[tk+3][tr]=wv.w;
        __syncthreads();
        #pragma unroll
        for(int kk=0;kk<16;kk++){
            float4 a4 = *(const float4*)&As[kk][ty*4];
            float4 w4 = *(const float4*)&Ws[kk][tx*4];
            float a[4] = {a4.x,a4.y,a4.z,a4.w};
            float w[4] = {w4.x,w4.y,w4.z,w4.w};
            #pragma unroll
            for(int i=0;i<4;i++)
                #pragma unroll
                for(int j=0;j<4;j++)
                    acc[i][j] = fmaf(a[i], w[j], acc[i][j]);
        }
    }
    #pragma unroll
    for(int i=0;i<4;i++){
        #pragma unroll
        for(int j=0;j<4;j++){
            int n = n0 + tx*4 + j;
            if(n < N){
                float val = acc[i][j];
                if(ACT==1) val = softplusf_(val + bias[n]);
                C[(size_t)(m0+ty*4+i)*ldc + n] = val;
            }
        }
    }
}

// ---- causal depthwise conv (k=4) + bias + SiLU; x is cols [0,DI) of xz ----
__global__ __launch_bounds__(256) void conv_silu_kernel(
        const float* __restrict__ xz,
        const float* __restrict__ cw,   // DI x 4
        const float* __restrict__ cb,   // DI
        float* __restrict__ out){       // MTOK x DI
    int idx = blockIdx.x*256 + threadIdx.x;   // over MTOK*DI
    int d = idx % DI;
    int tok = idx / DI;
    int l = tok % LSEQ;
    const float* xcol = xz + (size_t)tok*(2*DI) + d;
    float w0=cw[d*4+0], w1=cw[d*4+1], w2=cw[d*4+2], w3=cw[d*4+3];
    float acc = cb[d];
    acc = fmaf(w3, xcol[0], acc);
    if(l>=1) acc = fmaf(w2, xcol[-(2*DI)], acc);
    if(l>=2) acc = fmaf(w1, xcol[-2*(2*DI)], acc);
    if(l>=3) acc = fmaf(w0, xcol[-3*(2*DI)], acc);
    out[(size_t)tok*DI + d] = siluf_(acc);
}

// ---- selective scan: thread = (channel d, state s); 16-lane reduce for y ----
// fused: y = (scan_y + x*D) * silu(z)
__global__ __launch_bounds__(256) void scan_kernel(
        const float* __restrict__ dt,     // MTOK x DI
        const float* __restrict__ xconv,  // MTOK x DI
        const float* __restrict__ xdbl,   // MTOK x 80 (B at 48, C at 64)
        const float* __restrict__ xz,     // MTOK x 2*DI (z at +DI)
        const float* __restrict__ A_log,  // DI x DS
        const float* __restrict__ Dskip,  // DI
        float* __restrict__ y){           // MTOK x DI
    int tid = threadIdx.x;
    int s = tid & 15;
    int dloc = tid >> 4;                  // 0..15
    int b = blockIdx.x / (DI/16);
    int dgrp = blockIdx.x % (DI/16);
    int d = dgrp*16 + dloc;
    float A  = -__expf(A_log[d*DS + s]);
    float Dv = Dskip[d];
    float h = 0.f;
    size_t base = (size_t)b*LSEQ;
    for(int l=0;l<LSEQ;l++){
        size_t tok = base + l;
        float dtv = dt[tok*DI + d];
        float xv  = xconv[tok*DI + d];
        float Bv  = xdbl[tok*80 + DTR + s];
        float Cv  = xdbl[tok*80 + DTR + DS + s];
        float dA  = __expf(dtv*A);
        h = fmaf(dA, h, (dtv*xv)*Bv);
        float p = h*Cv;
        p += __shfl_xor(p, 8, 16);
        p += __shfl_xor(p, 4, 16);
        p += __shfl_xor(p, 2, 16);
        p += __shfl_xor(p, 1, 16);
        if(s==0){
            float zv = xz[tok*(2*DI) + DI + d];
            y[tok*DI + d] = (p + xv*Dv) * siluf_(zv);
        }
    }
}

extern "C" void kernel_launch(void* const* d_in, const int* in_sizes, int n_in,
                              void* d_out, int out_size, void* d_ws, size_t ws_size,
                              hipStream_t stream) {
    const float* emb        = (const float*)d_in[0];
    const float* norm_w     = (const float*)d_in[1];
    const float* norm_b     = (const float*)d_in[2];
    const float* in_proj_w  = (const float*)d_in[3];
    const float* conv_w     = (const float*)d_in[4];
    const float* conv_b     = (const float*)d_in[5];
    const float* x_proj_w   = (const float*)d_in[6];
    const float* dt_proj_w  = (const float*)d_in[7];
    const float* dt_proj_b  = (const float*)d_in[8];
    const float* A_log      = (const float*)d_in[9];
    const float* D_skip     = (const float*)d_in[10];
    const float* out_proj_w = (const float*)d_in[11];
    const float* norm_f_w   = (const float*)d_in[12];
    const float* norm_f_b   = (const float*)d_in[13];
    float* out = (float*)d_out;

    float* p = (float*)d_ws;
    float* residual = p; p += (size_t)MTOK*DM;
    float* normed   = p; p += (size_t)MTOK*DM;
    float* hidden   = p; p += (size_t)MTOK*DM;
    float* xz       = p; p += (size_t)MTOK*2*DI;
    float* xconv    = p; p += (size_t)MTOK*DI;
    float* xdbl     = p; p += (size_t)MTOK*80;
    float* dtbuf    = p; p += (size_t)MTOK*DI;
    float* ybuf     = p; p += (size_t)MTOK*DI;

    for(int i=0;i<NLAYER;i++){
        const float* hin = (i==0) ? emb : hidden;
        if(i==0)
            add_ln_kernel<1><<<MTOK,256,0,stream>>>(hin, residual, normed,
                                                    norm_w + (size_t)i*DM, norm_b + (size_t)i*DM);
        else
            add_ln_kernel<0><<<MTOK,256,0,stream>>>(hin, residual, normed,
                                                    norm_w + (size_t)i*DM, norm_b + (size_t)i*DM);
        {   // in_proj: (2048x768) @ (3072x768)^T -> xz
            dim3 g((2*DI)/64, MTOK/64);
            gemm_tn<0><<<g,256,0,stream>>>(normed, DM, in_proj_w + (size_t)i*2*DI*DM,
                                           nullptr, xz, 2*DI, MTOK, 2*DI, DM);
        }
        conv_silu_kernel<<<(MTOK*DI)/256,256,0,stream>>>(xz, conv_w + (size_t)i*DI*4,
                                                         conv_b + (size_t)i*DI, xconv);
        {   // x_proj: (2048x1536) @ (80x1536)^T -> xdbl
            dim3 g((80+63)/64, MTOK/64);
            gemm_tn<0><<<g,256,0,stream>>>(xconv, DI, x_proj_w + (size_t)i*80*DI,
                                           nullptr, xdbl, 80, MTOK, 80, DI);
        }
        {   // dt_proj: (2048x48 of xdbl) @ (1536x48)^T + bias, softplus -> dtbuf
            dim3 g(DI/64, MTOK/64);
            gemm_tn<1><<<g,256,0,stream>>>(xdbl, 80, dt_proj_w + (size_t)i*DI*DTR,
                                           dt_proj_b + (size_t)i*DI, dtbuf, DI, MTOK, DI, DTR);
        }
        scan_kernel<<<BATCH*(DI/16),256,0,stream>>>(dtbuf, xconv, xdbl, xz,
                                                    A_log + (size_t)i*DI*DS,
                                                    D_skip + (size_t)i*DI, ybuf);
        {   // out_proj: (2048x1536) @ (768x1536)^T -> hidden
            dim3 g(DM/64, MTOK/64);
            gemm_tn<0><<<g,256,0,stream>>>(ybuf, DI, out_proj_w + (size_t)i*DM*DI,
                                           nullptr, hidden, DM, MTOK, DM, DI);
        }
    }
    add_ln_kernel<0><<<MTOK,256,0,stream>>>(hidden, residual, out, norm_f_w, norm_f_b);
}

// Round 2
// 2053.473 us; speedup vs baseline: 2.1898x; 2.1898x over previous
//
#include <hip/hip_runtime.h>
#include <math.h>

#define DM 768
#define DI 1536
#define DS 16
#define DTR 48
#define NLAYER 4
#define LSEQ 1024
#define BATCH 2
#define MTOK (BATCH*LSEQ)
#define NCH 16
#define LC (LSEQ/NCH)   // 64

__device__ __forceinline__ float sigmoidf_(float x){ return 1.0f/(1.0f+__expf(-x)); }
__device__ __forceinline__ float siluf_(float x){ return x*sigmoidf_(x); }
__device__ __forceinline__ float softplusf_(float x){
    return fmaxf(x,0.0f) + log1pf(__expf(-fabsf(x)));
}

// ---- fused residual-add + LayerNorm (one block per token, 768 = 256*3) ----
template<int FIRST>
__global__ __launch_bounds__(256) void add_ln_kernel(
        const float* __restrict__ hidden,
        float* __restrict__ residual,
        float* __restrict__ out,
        const float* __restrict__ w,
        const float* __restrict__ b){
    int tok = blockIdx.x;
    int tid = threadIdx.x;
    const float* hrow = hidden + (size_t)tok*DM;
    float* rrow = residual + (size_t)tok*DM;
    float v[3];
    float s = 0.f, ss = 0.f;
    #pragma unroll
    for(int j=0;j<3;j++){
        int idx = tid + j*256;
        float r = FIRST ? 0.f : rrow[idx];
        float x = hrow[idx] + r;
        rrow[idx] = x;
        v[j] = x;
        s += x; ss += x*x;
    }
    __shared__ float red[2][4];
    #pragma unroll
    for(int off=32; off; off>>=1){ s += __shfl_down(s, off); ss += __shfl_down(ss, off); }
    int wave = tid>>6, lane = tid&63;
    if(lane==0){ red[0][wave]=s; red[1][wave]=ss; }
    __syncthreads();
    if(tid==0){
        float ts=0.f, tss=0.f;
        #pragma unroll
        for(int i=0;i<4;i++){ ts+=red[0][i]; tss+=red[1][i]; }
        red[0][0]=ts; red[1][0]=tss;
    }
    __syncthreads();
    float mean = red[0][0]*(1.0f/DM);
    float var  = red[1][0]*(1.0f/DM) - mean*mean;
    float rstd = rsqrtf(var + 1e-5f);
    #pragma unroll
    for(int j=0;j<3;j++){
        int idx = tid + j*256;
        out[(size_t)tok*DM + idx] = (v[j]-mean)*rstd*w[idx] + b[idx];
    }
}

// ---- generic fp32 GEMM: C[m][n] = act(sum_k A[m][k]*W[n][k] (+bias[n])) ----
template<int ACT>
__global__ __launch_bounds__(256) void gemm_tn(
        const float* __restrict__ A, int lda,
        const float* __restrict__ W,
        const float* __restrict__ bias,
        float* __restrict__ C, int ldc,
        int M, int N, int K){
    alignas(16) __shared__ float As[16][68];
    alignas(16) __shared__ float Ws[16][68];
    int tid = threadIdx.x;
    int m0 = blockIdx.y*64;
    int n0 = blockIdx.x*64;
    int tr = tid>>2;        // 0..63
    int tk = (tid&3)*4;     // 0,4,8,12
    int tx = tid&15, ty = tid>>4;
    float acc[4][4] = {};
    for(int k0=0;k0<K;k0+=16){
        float4 av = *(const float4*)(A + (size_t)(m0+tr)*lda + k0 + tk);
        float4 wv = make_float4(0.f,0.f,0.f,0.f);
        if(n0+tr < N) wv = *(const float4*)(W + (size_t)(n0+tr)*K + k0 + tk);
        __syncthreads();
        As[tk+0][tr]=av.x; As[tk+1][tr]=av.y; As[tk+2][tr]=av.z; As[tk+3][tr]=av.w;
        Ws[tk+0][tr]=wv.x; Ws[tk+1][tr]=wv.y; Ws[tk+2][tr]=wv.z; Ws[tk+3][tr]=wv.w;
        __syncthreads();
        #pragma unroll
        for(int kk=0;kk<16;kk++){
            float4 a4 = *(const float4*)&As[kk][ty*4];
            float4 w4 = *(const float4*)&Ws[kk][tx*4];
            float a[4] = {a4.x,a4.y,a4.z,a4.w};
            float w[4] = {w4.x,w4.y,w4.z,w4.w};
            #pragma unroll
            for(int i=0;i<4;i++)
                #pragma unroll
                for(int j=0;j<4;j++)
                    acc[i][j] = fmaf(a[i], w[j], acc[i][j]);
        }
    }
    #pragma unroll
    for(int i=0;i<4;i++){
        #pragma unroll
        for(int j=0;j<4;j++){
            int n = n0 + tx*4 + j;
            if(n < N){
                float val = acc[i][j];
                if(ACT==1) val = softplusf_(val + bias[n]);
                C[(size_t)(m0+ty*4+i)*ldc + n] = val;
            }
        }
    }
}

// ---- causal depthwise conv (k=4) + bias + SiLU ----
__global__ __launch_bounds__(256) void conv_silu_kernel(
        const float* __restrict__ xz,
        const float* __restrict__ cw,
        const float* __restrict__ cb,
        float* __restrict__ out){
    int idx = blockIdx.x*256 + threadIdx.x;
    int d = idx % DI;
    int tok = idx / DI;
    int l = tok % LSEQ;
    const float* xcol = xz + (size_t)tok*(2*DI) + d;
    float w0=cw[d*4+0], w1=cw[d*4+1], w2=cw[d*4+2], w3=cw[d*4+3];
    float acc = cb[d];
    acc = fmaf(w3, xcol[0], acc);
    if(l>=1) acc = fmaf(w2, xcol[-(2*DI)], acc);
    if(l>=2) acc = fmaf(w1, xcol[-2*(2*DI)], acc);
    if(l>=3) acc = fmaf(w0, xcol[-3*(2*DI)], acc);
    out[(size_t)tok*DI + d] = siluf_(acc);
}

// ==== chunked parallel selective scan ====
// Phase A: per-(b,chunk,d,s) local scan from h=0 over LC steps.
// Stores h_local and P = prod(dA) at [((b*NCH+c)*DI + d)*DS + s].
__global__ __launch_bounds__(256) void scan_local_kernel(
        const float* __restrict__ dt,     // MTOK x DI
        const float* __restrict__ xconv,  // MTOK x DI
        const float* __restrict__ xdbl,   // MTOK x 80 (B at 48)
        const float* __restrict__ A_log,  // DI x DS
        float* __restrict__ hfin,         // B*NCH*DI*DS
        float* __restrict__ pfin){
    int tid = threadIdx.x;
    int s = tid & 15;
    int dloc = tid >> 4;
    int dgrp = blockIdx.x % (DI/16);
    int c    = (blockIdx.x / (DI/16)) % NCH;
    int b    = blockIdx.x / ((DI/16)*NCH);
    int d = dgrp*16 + dloc;
    float A = -__expf(A_log[d*DS + s]);
    float h = 0.f, P = 1.f;
    size_t tok0 = (size_t)b*LSEQ + c*LC;
    #pragma unroll 4
    for(int l=0;l<LC;l++){
        size_t tok = tok0 + l;
        float dtv = dt[tok*DI + d];
        float xv  = xconv[tok*DI + d];
        float Bv  = xdbl[tok*80 + DTR + s];
        float dA  = __expf(dtv*A);
        P *= dA;
        h = fmaf(dA, h, (dtv*xv)*Bv);
    }
    size_t idx = ((size_t)(b*NCH + c)*DI + d)*DS + s;
    hfin[idx] = h;
    pfin[idx] = P;
}

// Phase B: serial chain over NCH chunk summaries; in-place converts
// hfin -> h_in (state at chunk entry).
__global__ __launch_bounds__(256) void scan_chain_kernel(
        float* __restrict__ hp,           // hfin in, h_in out
        const float* __restrict__ pf){
    int gid = blockIdx.x*256 + threadIdx.x;   // over B*DI*DS
    int b = gid / (DI*DS);
    int r = gid % (DI*DS);
    float h = 0.f;
    #pragma unroll
    for(int c=0;c<NCH;c++){
        size_t idx = ((size_t)(b*NCH + c))*(DI*DS) + r;
        float hf = hp[idx];
        float P  = pf[idx];
        hp[idx] = h;
        h = fmaf(P, h, hf);
    }
}

// Phase C: rerun local scan from h_in; emit y = (sum_s h*C + x*D)*silu(z).
__global__ __launch_bounds__(256) void scan_apply_kernel(
        const float* __restrict__ dt,
        const float* __restrict__ xconv,
        const float* __restrict__ xdbl,   // B at 48, C at 64
        const float* __restrict__ xz,     // z at +DI
        const float* __restrict__ A_log,
        const float* __restrict__ Dskip,
        const float* __restrict__ hin,    // B*NCH*DI*DS
        float* __restrict__ y){
    int tid = threadIdx.x;
    int s = tid & 15;
    int dloc = tid >> 4;
    int dgrp = blockIdx.x % (DI/16);
    int c    = (blockIdx.x / (DI/16)) % NCH;
    int b    = blockIdx.x / ((DI/16)*NCH);
    int d = dgrp*16 + dloc;
    float A  = -__expf(A_log[d*DS + s]);
    float Dv = Dskip[d];
    float h  = hin[((size_t)(b*NCH + c)*DI + d)*DS + s];
    size_t tok0 = (size_t)b*LSEQ + c*LC;
    #pragma unroll 2
    for(int l=0;l<LC;l++){
        size_t tok = tok0 + l;
        float dtv = dt[tok*DI + d];
        float xv  = xconv[tok*DI + d];
        float Bv  = xdbl[tok*80 + DTR + s];
        float Cv  = xdbl[tok*80 + DTR + DS + s];
        float dA  = __expf(dtv*A);
        h = fmaf(dA, h, (dtv*xv)*Bv);
        float p = h*Cv;
        p += __shfl_xor(p, 8, 16);
        p += __shfl_xor(p, 4, 16);
        p += __shfl_xor(p, 2, 16);
        p += __shfl_xor(p, 1, 16);
        if(s==0){
            float zv = xz[tok*(2*DI) + DI + d];
            y[tok*DI + d] = (p + xv*Dv) * siluf_(zv);
        }
    }
}

extern "C" void kernel_launch(void* const* d_in, const int* in_sizes, int n_in,
                              void* d_out, int out_size, void* d_ws, size_t ws_size,
                              hipStream_t stream) {
    const float* emb        = (const float*)d_in[0];
    const float* norm_w     = (const float*)d_in[1];
    const float* norm_b     = (const float*)d_in[2];
    const float* in_proj_w  = (const float*)d_in[3];
    const float* conv_w     = (const float*)d_in[4];
    const float* conv_b     = (const float*)d_in[5];
    const float* x_proj_w   = (const float*)d_in[6];
    const float* dt_proj_w  = (const float*)d_in[7];
    const float* dt_proj_b  = (const float*)d_in[8];
    const float* A_log      = (const float*)d_in[9];
    const float* D_skip     = (const float*)d_in[10];
    const float* out_proj_w = (const float*)d_in[11];
    const float* norm_f_w   = (const float*)d_in[12];
    const float* norm_f_b   = (const float*)d_in[13];
    float* out = (float*)d_out;

    float* p = (float*)d_ws;
    float* residual = p; p += (size_t)MTOK*DM;
    float* normed   = p; p += (size_t)MTOK*DM;
    float* hidden   = p; p += (size_t)MTOK*DM;
    float* xz       = p; p += (size_t)MTOK*2*DI;
    float* xconv    = p; p += (size_t)MTOK*DI;
    float* xdbl     = p; p += (size_t)MTOK*80;
    float* dtbuf    = p; p += (size_t)MTOK*DI;
    float* ybuf     = p; p += (size_t)MTOK*DI;
    float* hfin     = p; p += (size_t)BATCH*NCH*DI*DS;
    float* pfin     = p; p += (size_t)BATCH*NCH*DI*DS;

    for(int i=0;i<NLAYER;i++){
        const float* hin = (i==0) ? emb : hidden;
        if(i==0)
            add_ln_kernel<1><<<MTOK,256,0,stream>>>(hin, residual, normed,
                                                    norm_w + (size_t)i*DM, norm_b + (size_t)i*DM);
        else
            add_ln_kernel<0><<<MTOK,256,0,stream>>>(hin, residual, normed,
                                                    norm_w + (size_t)i*DM, norm_b + (size_t)i*DM);
        {   // in_proj
            dim3 g((2*DI)/64, MTOK/64);
            gemm_tn<0><<<g,256,0,stream>>>(normed, DM, in_proj_w + (size_t)i*2*DI*DM,
                                           nullptr, xz, 2*DI, MTOK, 2*DI, DM);
        }
        conv_silu_kernel<<<(MTOK*DI)/256,256,0,stream>>>(xz, conv_w + (size_t)i*DI*4,
                                                         conv_b + (size_t)i*DI, xconv);
        {   // x_proj
            dim3 g((80+63)/64, MTOK/64);
            gemm_tn<0><<<g,256,0,stream>>>(xconv, DI, x_proj_w + (size_t)i*80*DI,
                                           nullptr, xdbl, 80, MTOK, 80, DI);
        }
        {   // dt_proj (+bias, softplus)
            dim3 g(DI/64, MTOK/64);
            gemm_tn<1><<<g,256,0,stream>>>(xdbl, 80, dt_proj_w + (size_t)i*DI*DTR,
                                           dt_proj_b + (size_t)i*DI, dtbuf, DI, MTOK, DI, DTR);
        }
        {   // chunked parallel scan
            int nblkA = BATCH*NCH*(DI/16);
            scan_local_kernel<<<nblkA,256,0,stream>>>(dtbuf, xconv, xdbl,
                                                      A_log + (size_t)i*DI*DS, hfin, pfin);
            scan_chain_kernel<<<(BATCH*DI*DS)/256,256,0,stream>>>(hfin, pfin);
            scan_apply_kernel<<<nblkA,256,0,stream>>>(dtbuf, xconv, xdbl, xz,
                                                      A_log + (size_t)i*DI*DS,
                                                      D_skip + (size_t)i*DI, hfin, ybuf);
        }
        {   // out_proj
            dim3 g(DM/64, MTOK/64);
            gemm_tn<0><<<g,256,0,stream>>>(ybuf, DI, out_proj_w + (size_t)i*DM*DI,
                                           nullptr, hidden, DM, MTOK, DM, DI);
        }
    }
    add_ln_kernel<0><<<MTOK,256,0,stream>>>(hidden, residual, out, norm_f_w, norm_f_b);
}

// Round 4
// 1508.089 us; speedup vs baseline: 2.9817x; 1.3616x over previous
//
#include <hip/hip_runtime.h>
#include <math.h>

#define DM 768
#define DI 1536
#define DS 16
#define DTR 48
#define NLAYER 4
#define LSEQ 1024
#define BATCH 2
#define MTOK (BATCH*LSEQ)
#define NCH 16
#define LC (LSEQ/NCH)   // 64

typedef __attribute__((ext_vector_type(8))) __bf16 bf16x8;
typedef __attribute__((ext_vector_type(4))) float f32x4;

__device__ __forceinline__ float sigmoidf_(float x){ return 1.0f/(1.0f+__expf(-x)); }
__device__ __forceinline__ float siluf_(float x){ return x*sigmoidf_(x); }
__device__ __forceinline__ float softplusf_(float x){
    return fmaxf(x,0.0f) + log1pf(__expf(-fabsf(x)));
}

// ---- fused residual-add + LayerNorm ----
template<int FIRST>
__global__ __launch_bounds__(256) void add_ln_kernel(
        const float* __restrict__ hidden,
        float* __restrict__ residual,
        float* __restrict__ out,
        const float* __restrict__ w,
        const float* __restrict__ b){
    int tok = blockIdx.x;
    int tid = threadIdx.x;
    const float* hrow = hidden + (size_t)tok*DM;
    float* rrow = residual + (size_t)tok*DM;
    float v[3];
    float s = 0.f, ss = 0.f;
    #pragma unroll
    for(int j=0;j<3;j++){
        int idx = tid + j*256;
        float r = FIRST ? 0.f : rrow[idx];
        float x = hrow[idx] + r;
        rrow[idx] = x;
        v[j] = x;
        s += x; ss += x*x;
    }
    __shared__ float red[2][4];
    #pragma unroll
    for(int off=32; off; off>>=1){ s += __shfl_down(s, off); ss += __shfl_down(ss, off); }
    int wave = tid>>6, lane = tid&63;
    if(lane==0){ red[0][wave]=s; red[1][wave]=ss; }
    __syncthreads();
    if(tid==0){
        float ts=0.f, tss=0.f;
        #pragma unroll
        for(int i=0;i<4;i++){ ts+=red[0][i]; tss+=red[1][i]; }
        red[0][0]=ts; red[1][0]=tss;
    }
    __syncthreads();
    float mean = red[0][0]*(1.0f/DM);
    float var  = red[1][0]*(1.0f/DM) - mean*mean;
    float rstd = rsqrtf(var + 1e-5f);
    #pragma unroll
    for(int j=0;j<3;j++){
        int idx = tid + j*256;
        out[(size_t)tok*DM + idx] = (v[j]-mean)*rstd*w[idx] + b[idx];
    }
}

// ---- VALU fp32 GEMM (kept for small x_proj / dt_proj) ----
template<int ACT>
__global__ __launch_bounds__(256) void gemm_tn(
        const float* __restrict__ A, int lda,
        const float* __restrict__ W,
        const float* __restrict__ bias,
        float* __restrict__ C, int ldc,
        int M, int N, int K){
    alignas(16) __shared__ float As[16][68];
    alignas(16) __shared__ float Ws[16][68];
    int tid = threadIdx.x;
    int m0 = blockIdx.y*64;
    int n0 = blockIdx.x*64;
    int tr = tid>>2;
    int tk = (tid&3)*4;
    int tx = tid&15, ty = tid>>4;
    float acc[4][4] = {};
    for(int k0=0;k0<K;k0+=16){
        float4 av = *(const float4*)(A + (size_t)(m0+tr)*lda + k0 + tk);
        float4 wv = make_float4(0.f,0.f,0.f,0.f);
        if(n0+tr < N) wv = *(const float4*)(W + (size_t)(n0+tr)*K + k0 + tk);
        __syncthreads();
        As[tk+0][tr]=av.x; As[tk+1][tr]=av.y; As[tk+2][tr]=av.z; As[tk+3][tr]=av.w;
        Ws[tk+0][tr]=wv.x; Ws[tk+1][tr]=wv.y; Ws[tk+2][tr]=wv.z; Ws[tk+3][tr]=wv.w;
        __syncthreads();
        #pragma unroll
        for(int kk=0;kk<16;kk++){
            float4 a4 = *(const float4*)&As[kk][ty*4];
            float4 w4 = *(const float4*)&Ws[kk][tx*4];
            float a[4] = {a4.x,a4.y,a4.z,a4.w};
            float w[4] = {w4.x,w4.y,w4.z,w4.w};
            #pragma unroll
            for(int i=0;i<4;i++)
                #pragma unroll
                for(int j=0;j<4;j++)
                    acc[i][j] = fmaf(a[i], w[j], acc[i][j]);
        }
    }
    #pragma unroll
    for(int i=0;i<4;i++){
        #pragma unroll
        for(int j=0;j<4;j++){
            int n = n0 + tx*4 + j;
            if(n < N){
                float val = acc[i][j];
                if(ACT==1) val = softplusf_(val + bias[n]);
                C[(size_t)(m0+ty*4+i)*ldc + n] = val;
            }
        }
    }
}

// ---- split-bf16 MFMA GEMM: C = A(MxK) @ W(NxK)^T, fp32-accurate ----
// A = Ah + Al (bf16 truncation split), C = AhWh + AhWl + AlWh via
// mfma_f32_16x16x32_bf16. Tile 128x128, BK=64, 4 waves (64x64 each).
__device__ __forceinline__ void pack_hilo(float4 a, float4 b, uint4& hi, uint4& lo){
    unsigned ax=__float_as_uint(a.x), ay=__float_as_uint(a.y),
             az=__float_as_uint(a.z), aw=__float_as_uint(a.w);
    unsigned bx=__float_as_uint(b.x), by=__float_as_uint(b.y),
             bz=__float_as_uint(b.z), bw=__float_as_uint(b.w);
    hi.x = (ay & 0xffff0000u) | (ax >> 16);
    hi.y = (aw & 0xffff0000u) | (az >> 16);
    hi.z = (by & 0xffff0000u) | (bx >> 16);
    hi.w = (bw & 0xffff0000u) | (bz >> 16);
    float lx = a.x - __uint_as_float(ax & 0xffff0000u);
    float ly = a.y - __uint_as_float(ay & 0xffff0000u);
    float lz = a.z - __uint_as_float(az & 0xffff0000u);
    float lw = a.w - __uint_as_float(aw & 0xffff0000u);
    float mx = b.x - __uint_as_float(bx & 0xffff0000u);
    float my = b.y - __uint_as_float(by & 0xffff0000u);
    float mz = b.z - __uint_as_float(bz & 0xffff0000u);
    float mw = b.w - __uint_as_float(bw & 0xffff0000u);
    lo.x = (__float_as_uint(ly) & 0xffff0000u) | (__float_as_uint(lx) >> 16);
    lo.y = (__float_as_uint(lw) & 0xffff0000u) | (__float_as_uint(lz) >> 16);
    lo.z = (__float_as_uint(my) & 0xffff0000u) | (__float_as_uint(mx) >> 16);
    lo.w = (__float_as_uint(mw) & 0xffff0000u) | (__float_as_uint(mz) >> 16);
}

template<int SPLITK>
__global__ __launch_bounds__(256,2) void gemm_mfma(
        const float* __restrict__ A, int lda,
        const float* __restrict__ W,
        float* __restrict__ C, int ldc,
        int K){
    __shared__ uint4 ldsA[2][1024];   // [hi/lo][row*8 + swizzled granule], 32KB
    __shared__ uint4 ldsW[2][1024];   // 32KB
    const int tid = threadIdx.x;
    const int n0 = blockIdx.x*128;
    const int m0 = blockIdx.y*128;
    int kbeg = 0, kend = K;
    if(SPLITK > 1){ int ks = K/SPLITK; kbeg = blockIdx.z*ks; kend = kbeg + ks; }

    const int srow  = tid>>1;
    const int shalf = tid&1;
    const float* gA = A + (size_t)(m0+srow)*lda + shalf*32;
    const float* gW = W + (size_t)(n0+srow)*K   + shalf*32;

    const int lane = tid&63, wid = tid>>6;
    const int wr = wid>>1, wc = wid&1;
    const int lrow = lane&15, koff = lane>>4;
    const int arow = wr*64 + lrow;
    const int wrow = wc*64 + lrow;
    const int sel  = lrow & 7;

    f32x4 acc[4][4];
    #pragma unroll
    for(int r=0;r<4;r++)
        #pragma unroll
        for(int c=0;c<4;c++) acc[r][c] = (f32x4){0.f,0.f,0.f,0.f};

    for(int k0=kbeg; k0<kend; k0+=64){
        #pragma unroll
        for(int g=0; g<4; ++g){
            float4 x0 = *(const float4*)(gA + k0 + g*8);
            float4 x1 = *(const float4*)(gA + k0 + g*8 + 4);
            uint4 hi, lo; pack_hilo(x0, x1, hi, lo);
            int kk = shalf*4 + g;
            int slot = kk ^ (srow & 7);
            ldsA[0][srow*8 + slot] = hi;
            ldsA[1][srow*8 + slot] = lo;
        }
        #pragma unroll
        for(int g=0; g<4; ++g){
            float4 x0 = *(const float4*)(gW + k0 + g*8);
            float4 x1 = *(const float4*)(gW + k0 + g*8 + 4);
            uint4 hi, lo; pack_hilo(x0, x1, hi, lo);
            int kk = shalf*4 + g;
            int slot = kk ^ (srow & 7);
            ldsW[0][srow*8 + slot] = hi;
            ldsW[1][srow*8 + slot] = lo;
        }
        __syncthreads();
        #pragma unroll
        for(int s=0; s<2; ++s){
            bf16x8 ah[4], al[4], wh[4], wl[4];
            int slot = (s*4 + koff) ^ sel;
            #pragma unroll
            for(int r=0;r<4;r++){
                int idx = (arow + r*16)*8 + slot;
                ah[r] = __builtin_bit_cast(bf16x8, ldsA[0][idx]);
                al[r] = __builtin_bit_cast(bf16x8, ldsA[1][idx]);
            }
            #pragma unroll
            for(int c=0;c<4;c++){
                int idx = (wrow + c*16)*8 + slot;
                wh[c] = __builtin_bit_cast(bf16x8, ldsW[0][idx]);
                wl[c] = __builtin_bit_cast(bf16x8, ldsW[1][idx]);
            }
            #pragma unroll
            for(int r=0;r<4;r++){
                #pragma unroll
                for(int c=0;c<4;c++){
                    acc[r][c] = __builtin_amdgcn_mfma_f32_16x16x32_bf16(ah[r], wh[c], acc[r][c], 0,0,0);
                    acc[r][c] = __builtin_amdgcn_mfma_f32_16x16x32_bf16(ah[r], wl[c], acc[r][c], 0,0,0);
                    acc[r][c] = __builtin_amdgcn_mfma_f32_16x16x32_bf16(al[r], wh[c], acc[r][c], 0,0,0);
                }
            }
        }
        __syncthreads();
    }
    #pragma unroll
    for(int r=0;r<4;r++){
        #pragma unroll
        for(int c=0;c<4;c++){
            int col = n0 + wc*64 + c*16 + lrow;
            #pragma unroll
            for(int reg=0;reg<4;reg++){
                int row = m0 + wr*64 + r*16 + koff*4 + reg;
                if(SPLITK > 1)
                    atomicAdd(&C[(size_t)row*ldc + col], acc[r][c][reg]);
                else
                    C[(size_t)row*ldc + col] = acc[r][c][reg];
            }
        }
    }
}

// ---- causal depthwise conv (k=4) + bias + SiLU ----
__global__ __launch_bounds__(256) void conv_silu_kernel(
        const float* __restrict__ xz,
        const float* __restrict__ cw,
        const float* __restrict__ cb,
        float* __restrict__ out){
    int idx = blockIdx.x*256 + threadIdx.x;
    int d = idx % DI;
    int tok = idx / DI;
    int l = tok % LSEQ;
    const float* xcol = xz + (size_t)tok*(2*DI) + d;
    float w0=cw[d*4+0], w1=cw[d*4+1], w2=cw[d*4+2], w3=cw[d*4+3];
    float acc = cb[d];
    acc = fmaf(w3, xcol[0], acc);
    if(l>=1) acc = fmaf(w2, xcol[-(2*DI)], acc);
    if(l>=2) acc = fmaf(w1, xcol[-2*(2*DI)], acc);
    if(l>=3) acc = fmaf(w0, xcol[-3*(2*DI)], acc);
    out[(size_t)tok*DI + d] = siluf_(acc);
}

// ==== chunked parallel selective scan ====
__global__ __launch_bounds__(256) void scan_local_kernel(
        const float* __restrict__ dt,
        const float* __restrict__ xconv,
        const float* __restrict__ xdbl,
        const float* __restrict__ A_log,
        float* __restrict__ hfin,
        float* __restrict__ pfin){
    int tid = threadIdx.x;
    int s = tid & 15;
    int dloc = tid >> 4;
    int dgrp = blockIdx.x % (DI/16);
    int c    = (blockIdx.x / (DI/16)) % NCH;
    int b    = blockIdx.x / ((DI/16)*NCH);
    int d = dgrp*16 + dloc;
    float A = -__expf(A_log[d*DS + s]);
    float h = 0.f, P = 1.f;
    size_t tok0 = (size_t)b*LSEQ + c*LC;
    #pragma unroll 4
    for(int l=0;l<LC;l++){
        size_t tok = tok0 + l;
        float dtv = dt[tok*DI + d];
        float xv  = xconv[tok*DI + d];
        float Bv  = xdbl[tok*80 + DTR + s];
        float dA  = __expf(dtv*A);
        P *= dA;
        h = fmaf(dA, h, (dtv*xv)*Bv);
    }
    size_t idx = ((size_t)(b*NCH + c)*DI + d)*DS + s;
    hfin[idx] = h;
    pfin[idx] = P;
}

__global__ __launch_bounds__(256) void scan_chain_kernel(
        float* __restrict__ hp,
        const float* __restrict__ pf){
    int gid = blockIdx.x*256 + threadIdx.x;
    int b = gid / (DI*DS);
    int r = gid % (DI*DS);
    float h = 0.f;
    #pragma unroll
    for(int c=0;c<NCH;c++){
        size_t idx = ((size_t)(b*NCH + c))*(DI*DS) + r;
        float hf = hp[idx];
        float P  = pf[idx];
        hp[idx] = h;
        h = fmaf(P, h, hf);
    }
}

__global__ __launch_bounds__(256) void scan_apply_kernel(
        const float* __restrict__ dt,
        const float* __restrict__ xconv,
        const float* __restrict__ xdbl,
        const float* __restrict__ xz,
        const float* __restrict__ A_log,
        const float* __restrict__ Dskip,
        const float* __restrict__ hin,
        float* __restrict__ y){
    int tid = threadIdx.x;
    int s = tid & 15;
    int dloc = tid >> 4;
    int dgrp = blockIdx.x % (DI/16);
    int c    = (blockIdx.x / (DI/16)) % NCH;
    int b    = blockIdx.x / ((DI/16)*NCH);
    int d = dgrp*16 + dloc;
    float A  = -__expf(A_log[d*DS + s]);
    float Dv = Dskip[d];
    float h  = hin[((size_t)(b*NCH + c)*DI + d)*DS + s];
    size_t tok0 = (size_t)b*LSEQ + c*LC;
    #pragma unroll 2
    for(int l=0;l<LC;l++){
        size_t tok = tok0 + l;
        float dtv = dt[tok*DI + d];
        float xv  = xconv[tok*DI + d];
        float Bv  = xdbl[tok*80 + DTR + s];
        float Cv  = xdbl[tok*80 + DTR + DS + s];
        float dA  = __expf(dtv*A);
        h = fmaf(dA, h, (dtv*xv)*Bv);
        float p = h*Cv;
        p += __shfl_xor(p, 8, 16);
        p += __shfl_xor(p, 4, 16);
        p += __shfl_xor(p, 2, 16);
        p += __shfl_xor(p, 1, 16);
        if(s==0){
            float zv = xz[tok*(2*DI) + DI + d];
            y[tok*DI + d] = (p + xv*Dv) * siluf_(zv);
        }
    }
}

extern "C" void kernel_launch(void* const* d_in, const int* in_sizes, int n_in,
                              void* d_out, int out_size, void* d_ws, size_t ws_size,
                              hipStream_t stream) {
    const float* emb        = (const float*)d_in[0];
    const float* norm_w     = (const float*)d_in[1];
    const float* norm_b     = (const float*)d_in[2];
    const float* in_proj_w  = (const float*)d_in[3];
    const float* conv_w     = (const float*)d_in[4];
    const float* conv_b     = (const float*)d_in[5];
    const float* x_proj_w   = (const float*)d_in[6];
    const float* dt_proj_w  = (const float*)d_in[7];
    const float* dt_proj_b  = (const float*)d_in[8];
    const float* A_log      = (const float*)d_in[9];
    const float* D_skip     = (const float*)d_in[10];
    const float* out_proj_w = (const float*)d_in[11];
    const float* norm_f_w   = (const float*)d_in[12];
    const float* norm_f_b   = (const float*)d_in[13];
    float* out = (float*)d_out;

    float* p = (float*)d_ws;
    float* residual = p; p += (size_t)MTOK*DM;
    float* normed   = p; p += (size_t)MTOK*DM;
    float* hidden   = p; p += (size_t)MTOK*DM;
    float* xz       = p; p += (size_t)MTOK*2*DI;
    float* xconv    = p; p += (size_t)MTOK*DI;
    float* xdbl     = p; p += (size_t)MTOK*80;
    float* dtbuf    = p; p += (size_t)MTOK*DI;
    float* ybuf     = p; p += (size_t)MTOK*DI;
    float* hfin     = p; p += (size_t)BATCH*NCH*DI*DS;
    float* pfin     = p; p += (size_t)BATCH*NCH*DI*DS;

    for(int i=0;i<NLAYER;i++){
        const float* hin = (i==0) ? emb : hidden;
        if(i==0)
            add_ln_kernel<1><<<MTOK,256,0,stream>>>(hin, residual, normed,
                                                    norm_w + (size_t)i*DM, norm_b + (size_t)i*DM);
        else
            add_ln_kernel<0><<<MTOK,256,0,stream>>>(hin, residual, normed,
                                                    norm_w + (size_t)i*DM, norm_b + (size_t)i*DM);
        {   // in_proj: MFMA split-bf16, M=2048 N=3072 K=768
            dim3 g((2*DI)/128, MTOK/128, 1);
            gemm_mfma<1><<<g,256,0,stream>>>(normed, DM, in_proj_w + (size_t)i*2*DI*DM,
                                             xz, 2*DI, DM);
        }
        conv_silu_kernel<<<(MTOK*DI)/256,256,0,stream>>>(xz, conv_w + (size_t)i*DI*4,
                                                         conv_b + (size_t)i*DI, xconv);
        {   // x_proj (small): VALU path
            dim3 g((80+63)/64, MTOK/64);
            gemm_tn<0><<<g,256,0,stream>>>(xconv, DI, x_proj_w + (size_t)i*80*DI,
                                           nullptr, xdbl, 80, MTOK, 80, DI);
        }
        {   // dt_proj (K=48): VALU path
            dim3 g(DI/64, MTOK/64);
            gemm_tn<1><<<g,256,0,stream>>>(xdbl, 80, dt_proj_w + (size_t)i*DI*DTR,
                                           dt_proj_b + (size_t)i*DI, dtbuf, DI, MTOK, DI, DTR);
        }
        {   // chunked parallel scan
            int nblkA = BATCH*NCH*(DI/16);
            scan_local_kernel<<<nblkA,256,0,stream>>>(dtbuf, xconv, xdbl,
                                                      A_log + (size_t)i*DI*DS, hfin, pfin);
            scan_chain_kernel<<<(BATCH*DI*DS)/256,256,0,stream>>>(hfin, pfin);
            scan_apply_kernel<<<nblkA,256,0,stream>>>(dtbuf, xconv, xdbl, xz,
                                                      A_log + (size_t)i*DI*DS,
                                                      D_skip + (size_t)i*DI, hfin, ybuf);
        }
        {   // out_proj: MFMA split-bf16 + split-K=4, M=2048 N=768 K=1536
            hipMemsetAsync(hidden, 0, (size_t)MTOK*DM*sizeof(float), stream);
            dim3 g(DM/128, MTOK/128, 4);
            gemm_mfma<4><<<g,256,0,stream>>>(ybuf, DI, out_proj_w + (size_t)i*DM*DI,
                                             hidden, DM, DI);
        }
    }
    add_ln_kernel<0><<<MTOK,256,0,stream>>>(hidden, residual, out, norm_f_w, norm_f_b);
}

// Round 8
// 1204.590 us; speedup vs baseline: 3.7329x; 1.2520x over previous
//
#include <hip/hip_runtime.h>
#include <math.h>

#define DM 768
#define DI 1536
#define DS 16
#define DTR 48
#define NLAYER 4
#define LSEQ 1024
#define BATCH 2
#define MTOK (BATCH*LSEQ)
#define NCH 32
#define LC (LSEQ/NCH)   // 32

typedef __attribute__((ext_vector_type(8))) __bf16 bf16x8;
typedef __attribute__((ext_vector_type(4))) float f32x4;

__device__ __forceinline__ float sigmoidf_(float x){ return 1.0f/(1.0f+__expf(-x)); }
__device__ __forceinline__ float siluf_(float x){ return x*sigmoidf_(x); }
__device__ __forceinline__ float softplusf_(float x){
    return fmaxf(x,0.0f) + log1pf(__expf(-fabsf(x)));
}

// ---- fused residual-add + LayerNorm ----
template<int FIRST>
__global__ __launch_bounds__(256) void add_ln_kernel(
        const float* __restrict__ hidden,
        float* __restrict__ residual,
        float* __restrict__ out,
        const float* __restrict__ w,
        const float* __restrict__ b){
    int tok = blockIdx.x;
    int tid = threadIdx.x;
    const float* hrow = hidden + (size_t)tok*DM;
    float* rrow = residual + (size_t)tok*DM;
    float v[3];
    float s = 0.f, ss = 0.f;
    #pragma unroll
    for(int j=0;j<3;j++){
        int idx = tid + j*256;
        float r = FIRST ? 0.f : rrow[idx];
        float x = hrow[idx] + r;
        rrow[idx] = x;
        v[j] = x;
        s += x; ss += x*x;
    }
    __shared__ float red[2][4];
    #pragma unroll
    for(int off=32; off; off>>=1){ s += __shfl_down(s, off); ss += __shfl_down(ss, off); }
    int wave = tid>>6, lane = tid&63;
    if(lane==0){ red[0][wave]=s; red[1][wave]=ss; }
    __syncthreads();
    if(tid==0){
        float ts=0.f, tss=0.f;
        #pragma unroll
        for(int i=0;i<4;i++){ ts+=red[0][i]; tss+=red[1][i]; }
        red[0][0]=ts; red[1][0]=tss;
    }
    __syncthreads();
    float mean = red[0][0]*(1.0f/DM);
    float var  = red[1][0]*(1.0f/DM) - mean*mean;
    float rstd = rsqrtf(var + 1e-5f);
    #pragma unroll
    for(int j=0;j<3;j++){
        int idx = tid + j*256;
        out[(size_t)tok*DM + idx] = (v[j]-mean)*rstd*w[idx] + b[idx];
    }
}

// ---- split-bf16 MFMA GEMM: C = act(A(MxK) @ W(NxK)^T + bias) ----
// A = Ah + Al, C = AhWh + AhWl + AlWh. Tile 128x128, BK=64, 4 waves.
// Guards: N (store + W-row load), Kvalid (zero-fill K padding, mult of 8).
// NOTE: gA/gW are ROW bases only — the column offset lives entirely in
// colb = shalf*32 + g*8 (R5 bug was double-adding shalf*32).
__device__ __forceinline__ void pack_hilo(float4 a, float4 b, uint4& hi, uint4& lo){
    unsigned ax=__float_as_uint(a.x), ay=__float_as_uint(a.y),
             az=__float_as_uint(a.z), aw=__float_as_uint(a.w);
    unsigned bx=__float_as_uint(b.x), by=__float_as_uint(b.y),
             bz=__float_as_uint(b.z), bw=__float_as_uint(b.w);
    hi.x = (ay & 0xffff0000u) | (ax >> 16);
    hi.y = (aw & 0xffff0000u) | (az >> 16);
    hi.z = (by & 0xffff0000u) | (bx >> 16);
    hi.w = (bw & 0xffff0000u) | (bz >> 16);
    float lx = a.x - __uint_as_float(ax & 0xffff0000u);
    float ly = a.y - __uint_as_float(ay & 0xffff0000u);
    float lz = a.z - __uint_as_float(az & 0xffff0000u);
    float lw = a.w - __uint_as_float(aw & 0xffff0000u);
    float mx = b.x - __uint_as_float(bx & 0xffff0000u);
    float my = b.y - __uint_as_float(by & 0xffff0000u);
    float mz = b.z - __uint_as_float(bz & 0xffff0000u);
    float mw = b.w - __uint_as_float(bw & 0xffff0000u);
    lo.x = (__float_as_uint(ly) & 0xffff0000u) | (__float_as_uint(lx) >> 16);
    lo.y = (__float_as_uint(lw) & 0xffff0000u) | (__float_as_uint(lz) >> 16);
    lo.z = (__float_as_uint(my) & 0xffff0000u) | (__float_as_uint(mx) >> 16);
    lo.w = (__float_as_uint(mw) & 0xffff0000u) | (__float_as_uint(mz) >> 16);
}

template<int SPLITK, int ACT>
__global__ __launch_bounds__(256,2) void gemm_mfma(
        const float* __restrict__ A, int lda,
        const float* __restrict__ W, int wld,
        const float* __restrict__ bias,
        float* __restrict__ C, int ldc,
        int K, int Kvalid, int N){
    __shared__ uint4 ldsA[2][1024];
    __shared__ uint4 ldsW[2][1024];
    const int tid = threadIdx.x;
    const int n0 = blockIdx.x*128;
    const int m0 = blockIdx.y*128;
    int kbeg = 0, kend = K;
    if(SPLITK > 1){ int ks = K/SPLITK; kbeg = blockIdx.z*ks; kend = kbeg + ks; }

    const int srow  = tid>>1;
    const int shalf = tid&1;
    const float* gA = A + (size_t)(m0+srow)*lda;   // row base only
    const float* gW = W + (size_t)(n0+srow)*wld;   // row base only
    const bool wrow_ok = (n0+srow) < N;

    const int lane = tid&63, wid = tid>>6;
    const int wr = wid>>1, wc = wid&1;
    const int lrow = lane&15, koff = lane>>4;
    const int arow = wr*64 + lrow;
    const int wrow = wc*64 + lrow;
    const int sel  = lrow & 7;

    f32x4 acc[4][4];
    #pragma unroll
    for(int r=0;r<4;r++)
        #pragma unroll
        for(int c=0;c<4;c++) acc[r][c] = (f32x4){0.f,0.f,0.f,0.f};

    for(int k0=kbeg; k0<kend; k0+=64){
        #pragma unroll
        for(int g=0; g<4; ++g){
            int colb = shalf*32 + g*8;
            bool kv = (k0 + colb) < Kvalid;
            float4 x0 = make_float4(0.f,0.f,0.f,0.f), x1 = x0;
            if(kv){
                x0 = *(const float4*)(gA + k0 + colb);
                x1 = *(const float4*)(gA + k0 + colb + 4);
            }
            uint4 hi, lo; pack_hilo(x0, x1, hi, lo);
            int slot = (shalf*4 + g) ^ (srow & 7);
            ldsA[0][srow*8 + slot] = hi;
            ldsA[1][srow*8 + slot] = lo;
        }
        #pragma unroll
        for(int g=0; g<4; ++g){
            int colb = shalf*32 + g*8;
            bool kv = (k0 + colb) < Kvalid;
            float4 x0 = make_float4(0.f,0.f,0.f,0.f), x1 = x0;
            if(kv && wrow_ok){
                x0 = *(const float4*)(gW + k0 + colb);
                x1 = *(const float4*)(gW + k0 + colb + 4);
            }
            uint4 hi, lo; pack_hilo(x0, x1, hi, lo);
            int slot = (shalf*4 + g) ^ (srow & 7);
            ldsW[0][srow*8 + slot] = hi;
            ldsW[1][srow*8 + slot] = lo;
        }
        __syncthreads();
        #pragma unroll
        for(int s=0; s<2; ++s){
            bf16x8 ah[4], al[4], wh[4], wl[4];
            int slot = (s*4 + koff) ^ sel;
            #pragma unroll
            for(int r=0;r<4;r++){
                int idx = (arow + r*16)*8 + slot;
                ah[r] = __builtin_bit_cast(bf16x8, ldsA[0][idx]);
                al[r] = __builtin_bit_cast(bf16x8, ldsA[1][idx]);
            }
            #pragma unroll
            for(int c=0;c<4;c++){
                int idx = (wrow + c*16)*8 + slot;
                wh[c] = __builtin_bit_cast(bf16x8, ldsW[0][idx]);
                wl[c] = __builtin_bit_cast(bf16x8, ldsW[1][idx]);
            }
            #pragma unroll
            for(int r=0;r<4;r++){
                #pragma unroll
                for(int c=0;c<4;c++){
                    acc[r][c] = __builtin_amdgcn_mfma_f32_16x16x32_bf16(ah[r], wh[c], acc[r][c], 0,0,0);
                    acc[r][c] = __builtin_amdgcn_mfma_f32_16x16x32_bf16(ah[r], wl[c], acc[r][c], 0,0,0);
                    acc[r][c] = __builtin_amdgcn_mfma_f32_16x16x32_bf16(al[r], wh[c], acc[r][c], 0,0,0);
                }
            }
        }
        __syncthreads();
    }
    #pragma unroll
    for(int r=0;r<4;r++){
        #pragma unroll
        for(int c=0;c<4;c++){
            int col = n0 + wc*64 + c*16 + lrow;
            if(col < N){
                #pragma unroll
                for(int reg=0;reg<4;reg++){
                    int row = m0 + wr*64 + r*16 + koff*4 + reg;
                    float val = acc[r][c][reg];
                    if(ACT==1) val = softplusf_(val + bias[col]);
                    if(SPLITK > 1)
                        atomicAdd(&C[(size_t)row*ldc + col], val);
                    else
                        C[(size_t)row*ldc + col] = val;
                }
            }
        }
    }
}

// ---- causal depthwise conv (k=4) + bias + SiLU ----
__global__ __launch_bounds__(256) void conv_silu_kernel(
        const float* __restrict__ xz,
        const float* __restrict__ cw,
        const float* __restrict__ cb,
        float* __restrict__ out){
    int idx = blockIdx.x*256 + threadIdx.x;
    int d = idx % DI;
    int tok = idx / DI;
    int l = tok % LSEQ;
    const float* xcol = xz + (size_t)tok*(2*DI) + d;
    float w0=cw[d*4+0], w1=cw[d*4+1], w2=cw[d*4+2], w3=cw[d*4+3];
    float acc = cb[d];
    acc = fmaf(w3, xcol[0], acc);
    if(l>=1) acc = fmaf(w2, xcol[-(2*DI)], acc);
    if(l>=2) acc = fmaf(w1, xcol[-2*(2*DI)], acc);
    if(l>=3) acc = fmaf(w0, xcol[-3*(2*DI)], acc);
    out[(size_t)tok*DI + d] = siluf_(acc);
}

// ==== chunked parallel selective scan, register-state formulation ====
// Phase A: thread = (b, chunk, d); h[16] in registers; B/C staged in LDS.
__global__ __launch_bounds__(256) void scan_fused_kernel(
        float* dtS,                        // in: dt, out: cumsum S (in-place)
        const float* __restrict__ xconv,   // MTOK x DI
        const float* __restrict__ xdbl,    // MTOK x 80 (B at 48, C at 64)
        const float* __restrict__ A_log,   // DI x DS
        float* __restrict__ yloc,          // MTOK x DI
        float* __restrict__ hfin,          // B*NCH*DI*DS
        float* __restrict__ Sch,           // B*NCH*DI
        float* __restrict__ Abuf){         // DI*DS
    __shared__ float BC[LC][32];
    const int tid  = threadIdx.x;
    const int dblk = blockIdx.x % (DI/256);
    const int c    = (blockIdx.x / (DI/256)) % NCH;
    const int b    = blockIdx.x / ((DI/256)*NCH);
    const int d    = dblk*256 + tid;
    const int tok0 = b*LSEQ + c*LC;
    {   // stage B,C rows for the chunk: LC x 32 floats
        int t_tok = tid >> 3;
        int t_j   = (tid & 7)*4;
        *(float4*)&BC[t_tok][t_j] =
            *(const float4*)(xdbl + (size_t)(tok0 + t_tok)*80 + DTR + t_j);
    }
    float A[DS], h[DS];
    #pragma unroll
    for(int s=0;s<DS;s++){
        A[s] = -__expf(A_log[(size_t)d*DS + s]);
        h[s] = 0.f;
    }
    if(b==0 && c==0){
        #pragma unroll
        for(int s=0;s<DS;s++) Abuf[(size_t)d*DS + s] = A[s];
    }
    __syncthreads();
    float S = 0.f;
    #pragma unroll 2
    for(int l=0;l<LC;l++){
        size_t off = (size_t)(tok0 + l)*DI + d;
        float dtv = dtS[off];
        float xv  = xconv[off];
        S += dtv;
        float dtx = dtv*xv;
        float y = 0.f;
        #pragma unroll
        for(int q=0;q<4;q++){
            float4 B4 = *(const float4*)&BC[l][q*4];
            float4 C4 = *(const float4*)&BC[l][16+q*4];
            float dA;
            dA = __expf(dtv*A[4*q+0]); h[4*q+0]=fmaf(dA,h[4*q+0],dtx*B4.x); y=fmaf(h[4*q+0],C4.x,y);
            dA = __expf(dtv*A[4*q+1]); h[4*q+1]=fmaf(dA,h[4*q+1],dtx*B4.y); y=fmaf(h[4*q+1],C4.y,y);
            dA = __expf(dtv*A[4*q+2]); h[4*q+2]=fmaf(dA,h[4*q+2],dtx*B4.z); y=fmaf(h[4*q+2],C4.z,y);
            dA = __expf(dtv*A[4*q+3]); h[4*q+3]=fmaf(dA,h[4*q+3],dtx*B4.w); y=fmaf(h[4*q+3],C4.w,y);
        }
        yloc[off] = y;
        dtS[off]  = S;
    }
    size_t base = ((size_t)(b*NCH + c)*DI + d)*DS;
    #pragma unroll
    for(int q=0;q<4;q++)
        *(float4*)&hfin[base + q*4] = make_float4(h[q*4],h[q*4+1],h[q*4+2],h[q*4+3]);
    Sch[(size_t)(b*NCH + c)*DI + d] = S;
}

// Phase B: serial chain over NCH chunk summaries; hfin -> h_in (chunk entry).
__global__ __launch_bounds__(256) void scan_chain_kernel(
        float* __restrict__ hp,            // hfin in/out
        const float* __restrict__ Sch,
        const float* __restrict__ Abuf){
    int gid = blockIdx.x*256 + threadIdx.x;   // over B*DI*DS
    int b = gid / (DI*DS);
    int r = gid % (DI*DS);
    int d = r >> 4;
    float A = Abuf[r];
    float h = 0.f;
    #pragma unroll
    for(int c=0;c<NCH;c++){
        size_t idx = (size_t)(b*NCH + c)*(DI*DS) + r;
        float hf = hp[idx];
        float P  = __expf(A * Sch[(size_t)(b*NCH + c)*DI + d]);
        hp[idx] = h;
        h = fmaf(P, h, hf);
    }
}

// Phase C: fully parallel correction + D-skip + z-gating.
__global__ __launch_bounds__(256) void scan_correct_kernel(
        const float* __restrict__ xconv,
        const float* __restrict__ xdbl,
        const float* __restrict__ xz,
        const float* __restrict__ Abuf,
        const float* __restrict__ Dskip,
        const float* __restrict__ hin,     // B*NCH*DI*DS (chunk-entry state)
        const float* __restrict__ Sbuf,    // MTOK x DI (= dtS)
        float* __restrict__ y){            // in: yloc, out: final (in-place)
    int gid = blockIdx.x*256 + threadIdx.x;   // over MTOK*DI
    int d   = gid % DI;
    int tok = gid / DI;
    int b   = tok / LSEQ;
    int c   = (tok % LSEQ) / LC;
    float S  = Sbuf[gid];
    float yv = y[gid];
    size_t hb = ((size_t)(b*NCH + c)*DI + d)*DS;
    float corr = 0.f;
    #pragma unroll
    for(int q=0;q<4;q++){
        float4 hv = *(const float4*)&hin[hb + q*4];
        float4 Av = *(const float4*)&Abuf[(size_t)d*DS + q*4];
        float4 Cv = *(const float4*)&xdbl[(size_t)tok*80 + DTR + DS + q*4];
        corr = fmaf(hv.x*__expf(Av.x*S), Cv.x, corr);
        corr = fmaf(hv.y*__expf(Av.y*S), Cv.y, corr);
        corr = fmaf(hv.z*__expf(Av.z*S), Cv.z, corr);
        corr = fmaf(hv.w*__expf(Av.w*S), Cv.w, corr);
    }
    float xv = xconv[gid];
    float Dv = Dskip[d];
    float zv = xz[(size_t)tok*(2*DI) + DI + d];
    y[gid] = (yv + corr + xv*Dv) * siluf_(zv);
}

extern "C" void kernel_launch(void* const* d_in, const int* in_sizes, int n_in,
                              void* d_out, int out_size, void* d_ws, size_t ws_size,
                              hipStream_t stream) {
    const float* emb        = (const float*)d_in[0];
    const float* norm_w     = (const float*)d_in[1];
    const float* norm_b     = (const float*)d_in[2];
    const float* in_proj_w  = (const float*)d_in[3];
    const float* conv_w     = (const float*)d_in[4];
    const float* conv_b     = (const float*)d_in[5];
    const float* x_proj_w   = (const float*)d_in[6];
    const float* dt_proj_w  = (const float*)d_in[7];
    const float* dt_proj_b  = (const float*)d_in[8];
    const float* A_log      = (const float*)d_in[9];
    const float* D_skip     = (const float*)d_in[10];
    const float* out_proj_w = (const float*)d_in[11];
    const float* norm_f_w   = (const float*)d_in[12];
    const float* norm_f_b   = (const float*)d_in[13];
    float* out = (float*)d_out;

    float* p = (float*)d_ws;
    float* residual = p; p += (size_t)MTOK*DM;
    float* normed   = p; p += (size_t)MTOK*DM;
    float* hidden   = p; p += (size_t)MTOK*DM;
    float* xz       = p; p += (size_t)MTOK*2*DI;
    float* xconv    = p; p += (size_t)MTOK*DI;
    float* xdbl     = p; p += (size_t)MTOK*80;
    float* dtS      = p; p += (size_t)MTOK*DI;       // dt, then cumsum S (in-place)
    float* ybuf     = p; p += (size_t)MTOK*DI;       // yloc, then final y (in-place)
    float* hfin     = p; p += (size_t)BATCH*NCH*DI*DS;
    float* Sch      = p; p += (size_t)BATCH*NCH*DI;
    float* Abuf     = p; p += (size_t)DI*DS;

    for(int i=0;i<NLAYER;i++){
        const float* hin = (i==0) ? emb : hidden;
        if(i==0)
            add_ln_kernel<1><<<MTOK,256,0,stream>>>(hin, residual, normed,
                                                    norm_w + (size_t)i*DM, norm_b + (size_t)i*DM);
        else
            add_ln_kernel<0><<<MTOK,256,0,stream>>>(hin, residual, normed,
                                                    norm_w + (size_t)i*DM, norm_b + (size_t)i*DM);
        {   // in_proj: M=2048 N=3072 K=768
            dim3 g((2*DI)/128, MTOK/128, 1);
            gemm_mfma<1,0><<<g,256,0,stream>>>(normed, DM, in_proj_w + (size_t)i*2*DI*DM, DM,
                                               nullptr, xz, 2*DI, DM, DM, 2*DI);
        }
        conv_silu_kernel<<<(MTOK*DI)/256,256,0,stream>>>(xz, conv_w + (size_t)i*DI*4,
                                                         conv_b + (size_t)i*DI, xconv);
        {   // x_proj: M=2048 N=80 K=1536, split-K=8 with atomics
            hipMemsetAsync(xdbl, 0, (size_t)MTOK*80*sizeof(float), stream);
            dim3 g(1, MTOK/128, 8);
            gemm_mfma<8,0><<<g,256,0,stream>>>(xconv, DI, x_proj_w + (size_t)i*80*DI, DI,
                                               nullptr, xdbl, 80, DI, DI, 80);
        }
        {   // dt_proj: M=2048 N=1536 K=48 (padded to 64) + bias + softplus
            dim3 g(DI/128, MTOK/128, 1);
            gemm_mfma<1,1><<<g,256,0,stream>>>(xdbl, 80, dt_proj_w + (size_t)i*DI*DTR, DTR,
                                               dt_proj_b + (size_t)i*DI, dtS, DI, 64, DTR, DI);
        }
        {   // chunked scan: fused local -> chain -> parallel correct
            scan_fused_kernel<<<BATCH*NCH*(DI/256),256,0,stream>>>(
                dtS, xconv, xdbl, A_log + (size_t)i*DI*DS, ybuf, hfin, Sch, Abuf);
            scan_chain_kernel<<<(BATCH*DI*DS)/256,256,0,stream>>>(hfin, Sch, Abuf);
            scan_correct_kernel<<<(MTOK*DI)/256,256,0,stream>>>(
                xconv, xdbl, xz, Abuf, D_skip + (size_t)i*DI, hfin, dtS, ybuf);
        }
        {   // out_proj: M=2048 N=768 K=1536, split-K=4
            hipMemsetAsync(hidden, 0, (size_t)MTOK*DM*sizeof(float), stream);
            dim3 g(DM/128, MTOK/128, 4);
            gemm_mfma<4,0><<<g,256,0,stream>>>(ybuf, DI, out_proj_w + (size_t)i*DM*DI, DI,
                                               nullptr, hidden, DM, DI, DI, DM);
        }
    }
    add_ln_kernel<0><<<MTOK,256,0,stream>>>(hidden, residual, out, norm_f_w, norm_f_b);
}